// Round 2
// baseline (472.245 us; speedup 1.0000x reference)
//
#include <hip/hip_runtime.h>
#include <stdint.h>

#define T_FULL 2048
#define TT 128
#define NB_TOT 1025
#define KBANDS 36
#define EMBED 128
#define MAXF 130
#define FPAD 160
#define EPSV 1e-5f

typedef __attribute__((ext_vector_type(8))) short short8;
typedef __attribute__((ext_vector_type(4))) float floatx4;
typedef __attribute__((ext_vector_type(2))) float floatx2;

__device__ __forceinline__ void band_info(int band, int& nb, int& start) {
  if (band < 20)      { nb = 16; start = band << 4; }
  else if (band < 30) { nb = 32; start = 320 + ((band - 20) << 5); }
  else if (band < 35) { nb = 64; start = 640 + ((band - 30) << 6); }
  else                { nb = 65; start = 960; }
}

__device__ __forceinline__ unsigned short f2bf(float x) {  // RNE (prep only)
  union { float f; uint32_t u; } c; c.f = x;
  return (unsigned short)((c.u + 0x7FFFu + ((c.u >> 16) & 1u)) >> 16);
}

// ---- prologue: Wg = W*gamma (bf16, zero-padded to FPAD), S = sum_f Wg,
//      BB = b + W.beta.  One wave per (band, e) row.
__global__ void __launch_bounds__(256) prep_kernel(
    const float* __restrict__ W, const float* __restrict__ gamma,
    const float* __restrict__ beta, const float* __restrict__ bvec,
    unsigned short* __restrict__ Wg, float* __restrict__ S, float* __restrict__ BB)
{
  int k = blockIdx.x;
  int w = threadIdx.x >> 6, lane = threadIdx.x & 63;
  int e = blockIdx.y * 4 + w;
  int nb, start; band_info(k, nb, start);
  int f = nb * 2;
  const float* wrow = W + ((size_t)k * EMBED + e) * MAXF;
  const float* grow = gamma + (size_t)k * MAXF;
  const float* brow = beta + (size_t)k * MAXF;
  unsigned short* orow = Wg + ((size_t)k * EMBED + e) * FPAD;

  float bb = 0.f;
  int i1 = lane, i2 = lane + 64, i3 = lane + 128;
  float v1 = 0.f, v2 = 0.f, v3 = 0.f;
  if (i1 < f) { float wv = wrow[i1]; v1 = wv * grow[i1]; bb += wv * brow[i1]; }
  if (i2 < f) { float wv = wrow[i2]; v2 = wv * grow[i2]; bb += wv * brow[i2]; }
  if (i3 < f) { float wv = wrow[i3]; v3 = wv * grow[i3]; bb += wv * brow[i3]; }
  orow[i1] = f2bf(v1);
  orow[i2] = f2bf(v2);
  if (i3 < FPAD) orow[i3] = f2bf(v3);
  float s = v1 + v2 + v3;
  #pragma unroll
  for (int off = 32; off > 0; off >>= 1) {
    s  += __shfl_down(s, off);
    bb += __shfl_down(bb, off);
  }
  if (lane == 0) {
    S[k * EMBED + e]  = s;
    BB[k * EMBED + e] = bvec[k * EMBED + e] + bb;
  }
}

// ---- main, templated per band class.
// NBB = bins in band; LDSW = u32 words per LDS row (stride ≡ 4 mod 8 words
// + XOR swizzle → ds_write 2-way (free), ds_read_b128 uniform);
// KSTEPS = f/32 rounded up; FILL = zero-pad tail words (band 35 only).
// MFMA with A = x (m=t), B = Wg (n=e)  →  D row=t (4 consecutive per lane),
// col=e → float4 output stores.
template<int NBB, int LDSW, int KSTEPS, bool FILL, int MINW>
__global__ void __launch_bounds__(256, MINW) band_kernel(
    const float* __restrict__ spec, const unsigned short* __restrict__ Wg,
    const float* __restrict__ S, const float* __restrict__ BB,
    float* __restrict__ out, int band0, int start0)
{
  __shared__ uint32_t xn[TT * LDSW];
  __shared__ float part_s[4][64];
  __shared__ float part_q[4][64];
  __shared__ __align__(16) float mu_l[TT];
  __shared__ __align__(16) float rs_l[TT];

  int tid = threadIdx.x;
  int w = tid >> 6, lane = tid & 63;
  int band = band0 + blockIdx.y, b = blockIdx.z;
  int start = start0 + blockIdx.y * NBB;
  int t0 = blockIdx.x * TT;

  // ---- stage x tile (NBB bins x TT t) into LDS bf16, per-t stats.
  int tl = ((w & 1) << 6) | lane;          // local t 0..127
  uint32_t swz = ((tl >> 3) & 3) << 2;
  const floatx2* sp = (const floatx2*)spec +
      ((size_t)(b * NB_TOT + start) * T_FULL + (t0 + tl));
  float s = 0.f, q = 0.f;
  #pragma unroll
  for (int j = (w >> 1); j < NBB; j += 2) {
    floatx2 v = sp[(size_t)j * T_FULL];
    float re = v.x, im = v.y;
    s += re + im;
    q += re * re + im * im;
    uint32_t ure, uim;
    __builtin_memcpy(&ure, &re, 4);
    __builtin_memcpy(&uim, &im, 4);
    uint32_t pk = ((ure + 0x8000u) >> 16) | (((uim + 0x8000u) >> 16) << 16);
    xn[tl * LDSW + (j ^ swz)] = pk;
  }
  if (FILL) {   // zero tail words NBB .. KSTEPS*16-1 (swizzle-consistent)
    const int TW = KSTEPS * 16 - NBB;
    for (int idx = tid; idx < TT * TW; idx += 256) {
      int t = idx / TW, jz = NBB + idx % TW;
      xn[t * LDSW + (jz ^ (((t >> 3) & 3) << 2))] = 0;
    }
  }
  part_s[w][lane] = s;
  part_q[w][lane] = q;
  __syncthreads();
  if (tid < TT) {
    int h = tid >> 6, li = tid & 63;
    float su = part_s[h][li] + part_s[h + 2][li];
    float sq = part_q[h][li] + part_q[h + 2][li];
    const float inv_f = 1.0f / (float)(2 * NBB);
    float mu = su * inv_f;
    float var = sq * inv_f - mu * mu;
    mu_l[tid] = mu;
    rs_l[tid] = rsqrtf(var + EPSV);
  }
  __syncthreads();

  // ---- MFMA: D[t][e], wave w owns e rows [32w, 32w+32)
  int lane16 = lane & 15, quad = lane >> 4;
  floatx4 acc[2][8];
  #pragma unroll
  for (int i = 0; i < 2; ++i)
    #pragma unroll
    for (int j = 0; j < 8; ++j) acc[i][j] = floatx4{0.f, 0.f, 0.f, 0.f};

  int ebase = w * 32;
  const unsigned short* wgb = Wg + ((size_t)band * EMBED + ebase) * FPAD;
  #pragma unroll
  for (int kk = 0; kk < KSTEPS; ++kk) {
    // B-frag: B[k=quad*8+j][n=lane16] = Wg[e=lane16(+16)][kk*32+quad*8+j]
    short8 b0 = *(const short8*)(wgb + (size_t)lane16 * FPAD + kk * 32 + quad * 8);
    short8 b1 = *(const short8*)(wgb + (size_t)(16 + lane16) * FPAD + kk * 32 + quad * 8);
    #pragma unroll
    for (int nt = 0; nt < 8; ++nt) {
      int t = nt * 16 + lane16;
      int blk = kk * 4 + (quad ^ ((t >> 3) & 3));            // un-swizzle
      short8 afr = *(const short8*)&xn[t * LDSW + blk * 4];  // A[m=t][k], ds_read_b128
      acc[0][nt] = __builtin_amdgcn_mfma_f32_16x16x32_bf16(afr, b0, acc[0][nt], 0, 0, 0);
      acc[1][nt] = __builtin_amdgcn_mfma_f32_16x16x32_bf16(afr, b1, acc[1][nt], 0, 0, 0);
    }
  }

  // ---- epilogue: y = rstd*(G - mu*S) + BB; lane holds t = nt*16+quad*4+r,
  //      e = ebase + eb*16 + lane16 → float4 stores along t.
  int e_lo = ebase + lane16;
  const size_t row_stride = (size_t)KBANDS * T_FULL;
  float S0 = S[band * EMBED + e_lo],  S1 = S[band * EMBED + e_lo + 16];
  float B0 = BB[band * EMBED + e_lo], B1 = BB[band * EMBED + e_lo + 16];
  float* o0 = out + ((size_t)(b * EMBED + e_lo) * KBANDS + band) * T_FULL + t0 + quad * 4;
  float* o1 = o0 + 16 * row_stride;
  #pragma unroll
  for (int nt = 0; nt < 8; ++nt) {
    floatx4 mu4 = *(const floatx4*)&mu_l[nt * 16 + quad * 4];
    floatx4 rs4 = *(const floatx4*)&rs_l[nt * 16 + quad * 4];
    floatx4 y0, y1;
    #pragma unroll
    for (int r = 0; r < 4; ++r) {
      y0[r] = rs4[r] * (acc[0][nt][r] - mu4[r] * S0) + B0;
      y1[r] = rs4[r] * (acc[1][nt][r] - mu4[r] * S1) + B1;
    }
    *(floatx4*)(o0 + nt * 16) = y0;
    *(floatx4*)(o1 + nt * 16) = y1;
  }
}

extern "C" void kernel_launch(void* const* d_in, const int* in_sizes, int n_in,
                              void* d_out, int out_size, void* d_ws, size_t ws_size,
                              hipStream_t stream) {
  const float* spec  = (const float*)d_in[0];
  const float* gamma = (const float*)d_in[1];
  const float* beta  = (const float*)d_in[2];
  const float* W     = (const float*)d_in[3];
  const float* bvec  = (const float*)d_in[4];
  float* out = (float*)d_out;

  // ws layout: Wg bf16 [36][128][160] | S [36*128] f32 | BB [36*128] f32
  unsigned short* Wg = (unsigned short*)d_ws;
  size_t wg_bytes = (size_t)KBANDS * EMBED * FPAD * sizeof(unsigned short);
  float* S  = (float*)((char*)d_ws + wg_bytes);
  float* BB = S + KBANDS * EMBED;

  prep_kernel<<<dim3(KBANDS, 32), dim3(256), 0, stream>>>(W, gamma, beta, bvec, Wg, S, BB);
  // class A: 20 bands, nb=16 (f=32):  LDS row 20 words, 1 K-step
  band_kernel<16, 20, 1, false, 4><<<dim3(T_FULL / TT, 20, 8), dim3(256), 0, stream>>>(
      spec, Wg, S, BB, out, 0, 0);
  // class B: 10 bands, nb=32 (f=64):  LDS row 36 words, 2 K-steps
  band_kernel<32, 36, 2, false, 4><<<dim3(T_FULL / TT, 10, 8), dim3(256), 0, stream>>>(
      spec, Wg, S, BB, out, 20, 320);
  // class C1: 5 bands, nb=64 (f=128): LDS row 84 words, 4 K-steps
  band_kernel<64, 84, 4, false, 3><<<dim3(T_FULL / TT, 5, 8), dim3(256), 0, stream>>>(
      spec, Wg, S, BB, out, 30, 640);
  // class C2: band 35, nb=65 (f=130): LDS row 84 words, 5 K-steps + zero fill
  band_kernel<65, 84, 5, true, 3><<<dim3(T_FULL / TT, 1, 8), dim3(256), 0, stream>>>(
      spec, Wg, S, BB, out, 35, 960);
}